// Round 8
// baseline (366.081 us; speedup 1.0000x reference)
//
#include <hip/hip_runtime.h>
#include <stdint.h>

typedef short s16x8 __attribute__((ext_vector_type(8)));
typedef float f32x4 __attribute__((ext_vector_type(4)));

#define MFMA16(a, b, c) __builtin_amdgcn_mfma_f32_16x16x32_bf16((a), (b), (c), 0, 0, 0)

__device__ __forceinline__ ushort f2b(float f) {
  union { float f; uint32_t u; } x; x.f = f;
  uint32_t r = x.u + 0x7fffu + ((x.u >> 16) & 1u);
  return (ushort)(r >> 16);
}
__device__ __forceinline__ float b2f(ushort s) {
  union { uint32_t u; float f; } x; x.u = ((uint32_t)s) << 16;
  return x.f;
}
__device__ __forceinline__ uint32_t pack2t(float a, float b) {
  return __builtin_amdgcn_perm(__float_as_uint(b), __float_as_uint(a), 0x07060302u);
}
// RNE-packed bf16 pair: lo = bf16(a), hi = bf16(b). No builtin on gfx950 (m240).
__device__ __forceinline__ uint32_t cvtpk(float a, float b) {
  uint32_t r;
  asm("v_cvt_pk_bf16_f32 %0, %1, %2" : "=v"(r) : "v"(a), "v"(b));
  return r;
}

// Pin a precomputed value into a VGPR: opaque identity asm defeats the
// register allocator's rematerialization (round-8 theory: VGPR stuck at 92
// across rounds 0-7 despite hoisted address arrays => compiler recomputes
// addresses every iteration => the ~750 unexplained VALU ops/thread/iter).
#define PIN(x) asm volatile("" : "+v"(x))

// ---- counted barriers.
__device__ __forceinline__ void barrier_vm() {
  asm volatile("s_waitcnt vmcnt(0)" ::: "memory");
  __builtin_amdgcn_s_barrier();
}
__device__ __forceinline__ void barrier_vm4_lgkm() {
  asm volatile("s_waitcnt vmcnt(4) lgkmcnt(0)" ::: "memory");
  __builtin_amdgcn_s_barrier();
}
__device__ __forceinline__ void barrier_lgkm() {
  asm volatile("s_waitcnt lgkmcnt(0)" ::: "memory");
  __builtin_amdgcn_s_barrier();
}

// ---- single fused cast kernel: hidden (8192 blks) + Wq/Wk/Wv (3x1024) + dist (128)
__global__ __launch_bounds__(256) void cast_all(
    const float* __restrict__ hidden, const float* __restrict__ wq,
    const float* __restrict__ wk, const float* __restrict__ wv,
    const float* __restrict__ dist,
    ushort* __restrict__ hb, ushort* __restrict__ wb, ushort* __restrict__ eb) {
  int blk = blockIdx.x;
  const float* src; ushort* dst; int n;
  if (blk < 8192)      { src = hidden; dst = hb; n = 8388608; }
  else if (blk < 9216) { src = wq; dst = wb;               n = 1048576; blk -= 8192; }
  else if (blk < 10240){ src = wk; dst = wb + 1048576;     n = 1048576; blk -= 9216; }
  else if (blk < 11264){ src = wv; dst = wb + 2097152;     n = 1048576; blk -= 10240; }
  else                 { src = dist; dst = eb;             n = 131008;  blk -= 11264; }
  int i = (blk * 256 + threadIdx.x) * 4;
  if (i + 4 <= n) {
    float4 v = *(const float4*)(src + i);
    ushort4 o; o.x = f2b(v.x); o.y = f2b(v.y); o.z = f2b(v.z); o.w = f2b(v.w);
    *(ushort4*)(dst + i) = o;
  }
}

__device__ __forceinline__ void gload16(const void* g, void* l) {
  __builtin_amdgcn_global_load_lds((const __attribute__((address_space(1))) void*)g,
                                   (__attribute__((address_space(3))) void*)l, 16, 0, 0);
}

// ---------------- QKV GEMM v5 (byte-identical to round 7, passed).
__global__ __launch_bounds__(256) void qkv_gemm(
    const ushort* __restrict__ hb, const ushort* __restrict__ wb,
    const float* __restrict__ bq, const float* __restrict__ bk, const float* __restrict__ bv,
    ushort* __restrict__ qb, ushort* __restrict__ kb, ushort* __restrict__ vt) {
  __shared__ ushort As[3][4096];
  __shared__ ushort Bs[3][4096];
  const int tid = threadIdx.x;
  const int w = tid >> 6, lane = tid & 63, quad = lane >> 4, l16 = lane & 15;

  const int wg = blockIdx.x;
  const int swz = (wg & 7) * 192 + (wg >> 3);
  const int by = swz / 24;
  const int bx = swz % 24;
  const int m0 = by * 128, n0 = bx * 128;

  const int srow = w * 32 + (lane >> 2);
  const int scol = (lane & 3) * 8;
  const ushort* ga = hb + (size_t)(m0 + srow) * 1024 + scol;
  const ushort* gw = wb + (size_t)(n0 + srow) * 1024 + scol;

  f32x4 acc[4][4];
#pragma unroll
  for (int mt = 0; mt < 4; ++mt)
#pragma unroll
    for (int nt = 0; nt < 4; ++nt) acc[mt][nt] = (f32x4){0.f, 0.f, 0.f, 0.f};

  const int wm = (w >> 1) * 64, wn = (w & 1) * 64;

#define STAGE(C, K0)                                          \
  gload16(ga + (K0), As[C] + w * 1024);                       \
  gload16(ga + (K0) + 16 * 1024, As[C] + w * 1024 + 512);     \
  gload16(gw + (K0), Bs[C] + w * 1024);                       \
  gload16(gw + (K0) + 16 * 1024, Bs[C] + w * 1024 + 512);

#define COMPUTE(C)                                                           \
  {                                                                          \
    s16x8 af[4], bfr[4];                                                     \
    _Pragma("unroll")                                                        \
    for (int mt = 0; mt < 4; ++mt)                                           \
      af[mt] = *(const s16x8*)(As[C] + (wm + 16 * mt + l16) * 32 + quad * 8);\
    _Pragma("unroll")                                                        \
    for (int nt = 0; nt < 4; ++nt)                                           \
      bfr[nt] = *(const s16x8*)(Bs[C] + (wn + 16 * nt + l16) * 32 + quad * 8);\
    _Pragma("unroll")                                                        \
    for (int mt = 0; mt < 4; ++mt)                                           \
      _Pragma("unroll")                                                      \
      for (int nt = 0; nt < 4; ++nt)                                         \
        acc[mt][nt] = MFMA16(af[mt], bfr[nt], acc[mt][nt]);                  \
  }

  STAGE(0, 0)
  STAGE(1, 32)
#pragma unroll 1
  for (int tt = 0; tt < 10; ++tt) {
    const int k = tt * 96;
    barrier_vm4_lgkm(); STAGE(2, k + 64)  COMPUTE(0)
    barrier_vm4_lgkm(); STAGE(0, k + 96)  COMPUTE(1)
    barrier_vm4_lgkm(); STAGE(1, k + 128) COMPUTE(2)
  }
  barrier_vm4_lgkm(); COMPUTE(0)
  barrier_vm();       COMPUTE(1)
#undef STAGE
#undef COMPUTE

  const int mat = n0 >> 10;
  const int b = m0 >> 10;
  if (mat < 2) {
    ushort* outp = (mat == 0) ? qb : kb;
    const float* bias = (mat == 0) ? bq : bk;
#pragma unroll
    for (int mt = 0; mt < 4; ++mt) {
      int mbase = m0 + wm + 16 * mt + 4 * quad;
#pragma unroll
      for (int nt = 0; nt < 4; ++nt) {
        int n = n0 + wn + 16 * nt + l16;
        int o = n & 1023; int hh = o >> 6; int d = o & 63;
        float bsv = bias[o];
#pragma unroll
        for (int reg = 0; reg < 4; ++reg) {
          int l = (mbase + reg) & 1023;
          outp[(((size_t)(b * 16 + hh)) * 1024 + l) * 64 + d] = f2b(acc[mt][nt][reg] + bsv);
        }
      }
    }
  } else {
#pragma unroll
    for (int mt = 0; mt < 4; ++mt) {
      int mbase = m0 + wm + 16 * mt + 4 * quad;
      int lb = mbase & 1023;
#pragma unroll
      for (int nt = 0; nt < 4; ++nt) {
        int n = n0 + wn + 16 * nt + l16;
        int o = n & 1023; int hh = o >> 6; int d = o & 63;
        float bsv = bv[o];
        uint2 pk;
        pk.x = cvtpk(acc[mt][nt][0] + bsv, acc[mt][nt][1] + bsv);
        pk.y = cvtpk(acc[mt][nt][2] + bsv, acc[mt][nt][3] + bsv);
        *(uint2*)(vt + (((size_t)(b * 16 + hh)) * 64 + d) * 1024 + lb) = pk;
      }
    }
  }
}

// ---------------- Flash attention v7: round-7 code + PINNED address registers.
// Single change this round: every precomputed per-thread LDS address/constant
// is pinned into a VGPR so the allocator cannot rematerialize it per-iter.
#define KR  0
#define VR  8192
#define ER  16384
#define SER 28672
#define PR  35072

__global__ __launch_bounds__(256, 2) void attn_kernel(
    const ushort* __restrict__ qb, const ushort* __restrict__ kb,
    const ushort* __restrict__ vt, const ushort* __restrict__ eb,
    const float* __restrict__ mask, float* __restrict__ out) {
  __shared__ __align__(16) ushort sm[39168];
  const int tid = threadIdx.x;
  const int w = tid >> 6, lane = tid & 63, quad = lane >> 4, l16 = lane & 15;
  const int bh = blockIdx.y, b = bh >> 4, h = bh & 15;
  const int l0 = blockIdx.x * 64;

  const int srow = lane >> 3;                  // 0..7
  const int colb = ((lane & 7) ^ srow) * 8;    // swizzled 16B chunk on the global side
  const int row0 = w * 8 + srow;

  const ushort* kp = kb + ((size_t)bh * 1024 + row0) * 64 + colb;
  const ushort* vp = vt + ((size_t)bh * 64 + row0) * 1024 + colb;
  const float* maskp = mask + b * 1024 + l16;

  const int p0 = blockIdx.x % 3;               // E-ring segment of window start, it=0

  // ---- initial stage: Q -> PR, K(0) -> Kbuf0, V(0) -> Vbuf0, E window (128 rows)
  {
    const ushort* qp = qb + ((size_t)bh * 1024 + l0 + row0) * 64 + colb;
    gload16(qp,         sm + PR + w * 512);
    gload16(qp + 2048,  sm + PR + 2048 + w * 512);
    gload16(kp,         sm + KR + w * 512);
    gload16(kp + 2048,  sm + KR + 2048 + w * 512);
    gload16(vp,         sm + VR + w * 512);
    gload16(vp + 32768, sm + VR + 2048 + w * 512);
    const int t0i = l0 + 960;
#pragma unroll
    for (int c2 = 0; c2 < 4; ++c2) {
      int jb = w * 8 + 32 * c2;                // chunk base in window coords
      int seg = p0 + (jb >> 6); if (seg >= 3) seg -= 3;
      int t = t0i + jb + srow; if (t > 2046) t = 2046;
      gload16(eb + (size_t)t * 64 + colb, sm + ER + seg * 4096 + (jb & 63) * 64);
    }
  }

  // ---- hoisted per-thread constant addressing (swizzle term is lane-constant)
  const int lm7 = l16 & 7;
  const int swzq = (quad ^ lm7) * 8;           // cb=quad slice; cb=quad+4 is ^32
  int offR0[4], offR1[4];                      // rows 16nt+l16: K frags (S) + V frags (PV)
#pragma unroll
  for (int nt = 0; nt < 4; ++nt) {
    offR0[nt] = (16 * nt + l16) * 64 + swzq;
    offR1[nt] = offR0[nt] ^ 32;
    PIN(offR0[nt]); PIN(offR1[nt]);
  }
  int offW0 = (w * 16 + l16) * 64 + swzq;      // row w*16+l16
  int offW1 = offW0 ^ 32;
  int offPW0 = PR + offW0, offPW1 = PR + offW1;  // same row in P region (Q, P-as-A)
  PIN(offPW0); PIN(offPW1);
  // K-as-A frags for phase B: slab (3-w) (so E-blocks match phase A's w..w+4)
  int offWK0 = ((3 - w) * 16 + l16) * 64 + swzq;
  int offWK1 = offWK0 ^ 32;
  PIN(offWK0); PIN(offWK1);
  int eoffA[5]; bool selA[5];                  // shared E-block frag offsets + seg select
#pragma unroll
  for (int i = 0; i < 5; ++i) {
    int ba = w + i;
    eoffA[i] = ((ba & 3) * 16 + l16) * 64 + swzq;  selA[i] = (ba & 4) != 0;
    PIN(eoffA[i]);
  }
  int offSW[5];                                // SE2c band-store addresses (slab 3-w)
#pragma unroll
  for (int i = 0; i < 5; ++i) {
    offSW[i] = SER + (3 - w) * 1600 + (16 * i + l16) * 20 + 4 * quad;
    PIN(offSW[i]);
  }
  int bbF = SER + (w * 16 + 4 * quad + 15 - l16) * 20 + l16;  // SE2c read base
  PIN(bbF);
  int addrP[4][4];                             // P-scatter addresses (full)
#pragma unroll
  for (int nt = 0; nt < 4; ++nt)
#pragma unroll
    for (int reg = 0; reg < 4; ++reg) {
      addrP[nt][reg] = PR + (w * 16 + 4 * quad + reg) * 64
                     + (((2 * nt + (l16 >> 3)) ^ ((4 * quad + reg) & 7)) * 8) + lm7;
      PIN(addrP[nt][reg]);
    }
  int bidx[4]; bool bcnd[4];                   // bias1 bpermute constants
#pragma unroll
  for (int r = 0; r < 4; ++r) {
    bidx[r] = (quad * 16 + ((4 * quad + r + 15 - l16) & 15)) * 4;
    PIN(bidx[r]);
    bcnd[r] = (4 * quad + r) > l16;
  }

  barrier_vm();  // init: all staging landed (no lgkm ops outstanding)

  // hoist Q A-fragments (PR region is reused for P only after the P scatter of it=0)
  const s16x8 aq0 = *(const s16x8*)(sm + offPW0);
  const s16x8 aq1 = *(const s16x8*)(sm + offPW1);

  float rsum[4];
  f32x4 o_acc[4];
#pragma unroll
  for (int r = 0; r < 4; ++r) rsum[r] = 0.f;
#pragma unroll
  for (int nt = 0; nt < 4; ++nt) o_acc[nt] = (f32x4){0.f, 0.f, 0.f, 0.f};
  const f32x4 ZACC = {0.f, 0.f, 0.f, 0.f};     // persistent zero C-operand

  const float LOG2E = 1.44269504088896f;
  const float SC = 0.125f * LOG2E;

  int s0 = p0;  // ring segment holding window start, decremented mod 3 per iter

#define ATTN_ITER(P)                                                               \
  {                                                                                \
    const int it = 2 * ith + (P);                                                  \
    const int r0 = it * 64;                                                        \
    if (it > 0) barrier_vm(); /* X: prefetch landed; prior ds_reads consumed */    \
    /* ---- prefetch it+1 into buf[1-P] + E seg (stays in flight across C) */      \
    {                                                                              \
      const int rn = (r0 + 64) & 1023;                                             \
      gload16(kp + rn * 64,        sm + KR + 4096 * (1 - (P)) + w * 512);          \
      gload16(kp + rn * 64 + 2048, sm + KR + 4096 * (1 - (P)) + 2048 + w * 512);   \
      gload16(vp + rn,             sm + VR + 4096 * (1 - (P)) + w * 512);          \
      gload16(vp + rn + 32768,     sm + VR + 4096 * (1 - (P)) + 2048 + w * 512);   \
      int pnew = s0 + 2; if (pnew >= 3) pnew -= 3;                                 \
      const int tb = l0 + 960 - r0 - 64;                                           \
      _Pragma("unroll")                                                            \
      for (int c2 = 0; c2 < 2; ++c2) {                                             \
        int o = w * 8 + 32 * c2;                                                   \
        int t = tb + o + srow; t = t < 0 ? 0 : (t > 2046 ? 2046 : t);              \
        gload16(eb + (size_t)t * 64 + colb, sm + ER + pnew * 4096 + o * 64);       \
      }                                                                            \
    }                                                                              \
    float mkv[4];                                                                  \
    _Pragma("unroll")                                                              \
    for (int nt = 0; nt < 4; ++nt) mkv[nt] = maskp[r0 + 16 * nt] * LOG2E;          \
    const int sA4 = s0 * 4096;                                                     \
    int sBi = s0 + 1; if (sBi >= 3) sBi -= 3;                                      \
    const int sB4 = sBi * 4096;                                                    \
    const ushort* KbP = sm + KR + 4096 * (P);                                      \
    /* ---- S = Q K^T (MFMA cluster 1) */                                          \
    __builtin_amdgcn_s_setprio(1);                                                 \
    f32x4 zv[4];                                                                   \
    _Pragma("unroll")                                                              \
    for (int nt = 0; nt < 4; ++nt) {                                               \
      s16x8 bk0 = *(const s16x8*)(KbP + offR0[nt]);                                \
      s16x8 bk1 = *(const s16x8*)(KbP + offR1[nt]);                                \
      f32x4 z = MFMA16(aq0, bk0, ZACC);                                            \
      zv[nt] = MFMA16(aq1, bk1, z);                                                \
    }                                                                              \
    /* ---- merged E phases: read E block ONCE, feed Q·E (bias1) and K·E (band) */ \
    const s16x8 ak0 = *(const s16x8*)(KbP + offWK0);                               \
    const s16x8 ak1 = *(const s16x8*)(KbP + offWK1);                               \
    f32x4 d1[5];                                                                   \
    _Pragma("unroll")                                                              \
    for (int i = 0; i < 5; ++i) {                                                  \
      int ea = (selA[i] ? sB4 : sA4) + eoffA[i];                                   \
      s16x8 be0 = *(const s16x8*)(sm + ER + ea);                                   \
      s16x8 be1 = *(const s16x8*)(sm + ER + (ea ^ 32));                            \
      f32x4 z = MFMA16(aq0, be0, ZACC);                                            \
      d1[i] = MFMA16(aq1, be1, z);                                                 \
      f32x4 y = MFMA16(ak0, be0, ZACC);                                            \
      y = MFMA16(ak1, be1, y);                                                     \
      uint2 pk; pk.x = pack2t(y[0], y[1]); pk.y = pack2t(y[2], y[3]);              \
      *(uint2*)(sm + offSW[i]) = pk;                                               \
    }                                                                              \
    __builtin_amdgcn_s_setprio(0);                                                 \
    /* ---- bias1 (Q-side) via intra-wave bpermute */                              \
    _Pragma("unroll")                                                              \
    for (int r = 0; r < 4; ++r) {                                                  \
      float bp[5];                                                                 \
      _Pragma("unroll")                                                            \
      for (int i = 0; i < 5; ++i)                                                  \
        bp[i] = __int_as_float(                                                    \
            __builtin_amdgcn_ds_bpermute(bidx[r], __float_as_int(d1[i][r])));      \
      _Pragma("unroll")                                                            \
      for (int nt = 0; nt < 4; ++nt)                                               \
        zv[nt][r] += bcnd[r] ? bp[4 - nt] : bp[3 - nt];                            \
    }                                                                              \
    barrier_lgkm();  /* C: SE2c visible; prefetches NOT drained */                 \
    /* ---- bias2 + scale + mask -> p = exp2(z2); static softmax */                \
    _Pragma("unroll")                                                              \
    for (int nt = 0; nt < 4; ++nt) {                                               \
      _Pragma("unroll")                                                            \
      for (int reg = 0; reg < 4; ++reg) {                                          \
        float z2 = (zv[nt][reg] + b2f(sm[bbF + nt * 1600 + reg * 20])) * SC        \
                 + mkv[nt];                                                        \
        float pe = exp2f(z2);                                                      \
        zv[nt][reg] = pe;                                                          \
        rsum[reg] += pe;                                                           \
      }                                                                            \
    }                                                                              \
    /* ---- P scatter (rows wave-private -> no barrier; cvt_pk pairs) */           \
    _Pragma("unroll")                                                              \
    for (int nt = 0; nt < 4; ++nt) {                                               \
      uint32_t u01 = cvtpk(zv[nt][0], zv[nt][1]);                                  \
      uint32_t u23 = cvtpk(zv[nt][2], zv[nt][3]);                                  \
      sm[addrP[nt][0]] = (ushort)u01;                                              \
      sm[addrP[nt][1]] = (ushort)(u01 >> 16);                                      \
      sm[addrP[nt][2]] = (ushort)u23;                                              \
      sm[addrP[nt][3]] = (ushort)(u23 >> 16);                                      \
    }                                                                              \
    /* ---- O += P @ V (MFMA cluster 3; same-wave DS order + lgkmcnt suffice) */   \
    __builtin_amdgcn_s_setprio(1);                                                 \
    {                                                                              \
      const ushort* VbP = sm + VR + 4096 * (P);                                    \
      const s16x8 ap0 = *(const s16x8*)(sm + offPW0);                              \
      _Pragma("unroll")                                                            \
      for (int nt = 0; nt < 4; ++nt) {                                             \
        s16x8 bv0 = *(const s16x8*)(VbP + offR0[nt]);                              \
        o_acc[nt] = MFMA16(ap0, bv0, o_acc[nt]);                                   \
      }                                                                            \
      const s16x8 ap1 = *(const s16x8*)(sm + offPW1);                              \
      _Pragma("unroll")                                                            \
      for (int nt = 0; nt < 4; ++nt) {                                             \
        s16x8 bv1 = *(const s16x8*)(VbP + offR1[nt]);                              \
        o_acc[nt] = MFMA16(ap1, bv1, o_acc[nt]);                                   \
      }                                                                            \
    }                                                                              \
    __builtin_amdgcn_s_setprio(0);                                                 \
    s0 = (s0 == 0) ? 2 : s0 - 1;  /* window slides down 64 rows */                 \
  }

#pragma unroll 1
  for (int ith = 0; ith < 8; ++ith) {
    ATTN_ITER(0)
    ATTN_ITER(1)
  }
#undef ATTN_ITER

  // ---- final denominator reduce (once, not per-iter) + store
#pragma unroll
  for (int off = 1; off < 16; off <<= 1)
#pragma unroll
    for (int reg = 0; reg < 4; ++reg)
      rsum[reg] += __shfl_xor(rsum[reg], off);

#pragma unroll
  for (int nt = 0; nt < 4; ++nt)
#pragma unroll
    for (int reg = 0; reg < 4; ++reg) {
      int l = l0 + w * 16 + 4 * quad + reg;
      int d = 16 * nt + l16;
      out[((size_t)(b * 1024 + l)) * 1024 + h * 64 + d] = o_acc[nt][reg] / rsum[reg];
    }
}

// ---------------- host launch
extern "C" void kernel_launch(void* const* d_in, const int* in_sizes, int n_in,
                              void* d_out, int out_size, void* d_ws, size_t ws_size,
                              hipStream_t stream) {
  const float* hidden = (const float*)d_in[0];
  const float* mask   = (const float*)d_in[1];
  const float* Wq     = (const float*)d_in[2];
  const float* bq     = (const float*)d_in[3];
  const float* Wk     = (const float*)d_in[4];
  const float* bk     = (const float*)d_in[5];
  const float* Wv     = (const float*)d_in[6];
  const float* bv     = (const float*)d_in[7];
  const float* dist   = (const float*)d_in[8];
  float* out = (float*)d_out;

  ushort* ws = (ushort*)d_ws;
  ushort* qb = ws;
  ushort* kb = ws + 8388608;
  ushort* vt = ws + 16777216;
  ushort* hb = ws + 25165824;
  ushort* wb = ws + 33554432;
  ushort* eb = ws + 36700160;

  cast_all<<<11392, 256, 0, stream>>>(hidden, Wq, Wk, Wv, dist, hb, wb, eb);
  qkv_gemm<<<1536, 256, 0, stream>>>(hb, wb, bq, bk, bv, qb, kb, vt);
  attn_kernel<<<dim3(16, 128), 256, 0, stream>>>(qb, kb, vt, eb, mask, out);
}

// Round 9
// 340.140 us; speedup vs baseline: 1.0763x; 1.0763x over previous
//
#include <hip/hip_runtime.h>
#include <stdint.h>

typedef short s16x8 __attribute__((ext_vector_type(8)));
typedef float f32x4 __attribute__((ext_vector_type(4)));

#define MFMA16(a, b, c) __builtin_amdgcn_mfma_f32_16x16x32_bf16((a), (b), (c), 0, 0, 0)

__device__ __forceinline__ ushort f2b(float f) {
  union { float f; uint32_t u; } x; x.f = f;
  uint32_t r = x.u + 0x7fffu + ((x.u >> 16) & 1u);
  return (ushort)(r >> 16);
}
__device__ __forceinline__ float b2f(ushort s) {
  union { uint32_t u; float f; } x; x.u = ((uint32_t)s) << 16;
  return x.f;
}
__device__ __forceinline__ uint32_t pack2t(float a, float b) {
  return __builtin_amdgcn_perm(__float_as_uint(b), __float_as_uint(a), 0x07060302u);
}
// RNE-packed bf16 pair: lo = bf16(a), hi = bf16(b). No builtin on gfx950 (m240).
__device__ __forceinline__ uint32_t cvtpk(float a, float b) {
  uint32_t r;
  asm("v_cvt_pk_bf16_f32 %0, %1, %2" : "=v"(r) : "v"(a), "v"(b));
  return r;
}

// ---- barriers.
__device__ __forceinline__ void barrier_vm() {
  asm volatile("s_waitcnt vmcnt(0)" ::: "memory");
  __builtin_amdgcn_s_barrier();
}
__device__ __forceinline__ void barrier_vm_lgkm() {
  asm volatile("s_waitcnt vmcnt(0) lgkmcnt(0)" ::: "memory");
  __builtin_amdgcn_s_barrier();
}
__device__ __forceinline__ void barrier_lgkm() {
  asm volatile("s_waitcnt lgkmcnt(0)" ::: "memory");
  __builtin_amdgcn_s_barrier();
}

// ---- single fused cast kernel: hidden (8192 blks) + Wq/Wk/Wv (3x1024) + dist (128)
__global__ __launch_bounds__(256) void cast_all(
    const float* __restrict__ hidden, const float* __restrict__ wq,
    const float* __restrict__ wk, const float* __restrict__ wv,
    const float* __restrict__ dist,
    ushort* __restrict__ hb, ushort* __restrict__ wb, ushort* __restrict__ eb) {
  int blk = blockIdx.x;
  const float* src; ushort* dst; int n;
  if (blk < 8192)      { src = hidden; dst = hb; n = 8388608; }
  else if (blk < 9216) { src = wq; dst = wb;               n = 1048576; blk -= 8192; }
  else if (blk < 10240){ src = wk; dst = wb + 1048576;     n = 1048576; blk -= 9216; }
  else if (blk < 11264){ src = wv; dst = wb + 2097152;     n = 1048576; blk -= 10240; }
  else                 { src = dist; dst = eb;             n = 131008;  blk -= 11264; }
  int i = (blk * 256 + threadIdx.x) * 4;
  if (i + 4 <= n) {
    float4 v = *(const float4*)(src + i);
    ushort4 o; o.x = f2b(v.x); o.y = f2b(v.y); o.z = f2b(v.z); o.w = f2b(v.w);
    *(ushort4*)(dst + i) = o;
  }
}

__device__ __forceinline__ void gload16(const void* g, void* l) {
  __builtin_amdgcn_global_load_lds((const __attribute__((address_space(1))) void*)g,
                                   (__attribute__((address_space(3))) void*)l, 16, 0, 0);
}

// ---------------- QKV GEMM v6: 256x128 tile, 128x64 per wave, 3 blocks/CU.
// Diagnosis (r8): 128^2 gemm is ~84% DS-pipe-bound (12 waves x 8 ds_read_b128
// x 12cy = 1152cy vs ~1375cy/K-step). DS per FLOP ~ (1/BMw + 1/BNw): the
// 64x64 wave-tile pays 8 b128 / 256K FLOP; a 128x64 wave-tile pays 12 / 512K
// = 0.75x. BM=256 x BN=128 with 4 waves (2x2) gives 768 blocks = 3/CU x 256
// = ONE perfectly balanced round (LDS 48KB). VGPR target <=170 for 3/SIMD:
// acc 128 + af[4]+bfr[4] (A consumed in two 64-row halves) ~ 165.
__global__ __launch_bounds__(256, 3) void qkv_gemm(
    const ushort* __restrict__ hb, const ushort* __restrict__ wb,
    const float* __restrict__ bq, const float* __restrict__ bk, const float* __restrict__ bv,
    ushort* __restrict__ qb, ushort* __restrict__ kb, ushort* __restrict__ vt) {
  __shared__ ushort As[2][8192];   // 256 rows x 32 us ([row][32] -> 64B rows, conflict-free)
  __shared__ ushort Bs[2][4096];   // 128 rows x 32 us
  const int tid = threadIdx.x;
  const int w = tid >> 6, lane = tid & 63, quad = lane >> 4, l16 = lane & 15;

  // bijective XCD swizzle (768 % 8 == 0): consecutive tiles share an A-panel
  const int wg = blockIdx.x;
  const int swz = (wg & 7) * 96 + (wg >> 3);
  const int by = swz / 24;
  const int bx = swz % 24;
  const int m0 = by * 256, n0 = bx * 128;

  // staging: 1KB wave-chunks (wave-uniform LDS base; lane writes lane*16B).
  // chunk c covers rows 16c..16c+15: lane -> row 16c+(lane>>2), col (lane&3)*16B.
  const int arow = lane >> 2;
  const int acol = (lane & 3) * 8;
  const ushort* ga = hb + (size_t)(m0 + arow) * 1024 + acol;
  const ushort* gw = wb + (size_t)(n0 + arow) * 1024 + acol;

  f32x4 acc[8][4];
#pragma unroll
  for (int mt = 0; mt < 8; ++mt)
#pragma unroll
    for (int nt = 0; nt < 4; ++nt) acc[mt][nt] = (f32x4){0.f, 0.f, 0.f, 0.f};

  const int wm = (w >> 1) * 128, wn = (w & 1) * 64;

#define STAGE(C, K0)                                                      \
  gload16(ga + (K0) + (size_t)((w)      * 16) * 1024, As[C] + (w)      * 512); \
  gload16(ga + (K0) + (size_t)((w + 4)  * 16) * 1024, As[C] + (w + 4)  * 512); \
  gload16(ga + (K0) + (size_t)((w + 8)  * 16) * 1024, As[C] + (w + 8)  * 512); \
  gload16(ga + (K0) + (size_t)((w + 12) * 16) * 1024, As[C] + (w + 12) * 512); \
  gload16(gw + (K0) + (size_t)((w)      * 16) * 1024, Bs[C] + (w)      * 512); \
  gload16(gw + (K0) + (size_t)((w + 4)  * 16) * 1024, Bs[C] + (w + 4)  * 512);

#define COMPUTE(C)                                                            \
  {                                                                           \
    s16x8 bfr[4];                                                             \
    _Pragma("unroll")                                                         \
    for (int nt = 0; nt < 4; ++nt)                                            \
      bfr[nt] = *(const s16x8*)(Bs[C] + (wn + 16 * nt + l16) * 32 + quad * 8);\
    _Pragma("unroll")                                                         \
    for (int half = 0; half < 2; ++half) {                                    \
      s16x8 af[4];                                                            \
      _Pragma("unroll")                                                       \
      for (int mt = 0; mt < 4; ++mt)                                          \
        af[mt] = *(const s16x8*)(As[C] +                                      \
                    (wm + 64 * half + 16 * mt + l16) * 32 + quad * 8);        \
      _Pragma("unroll")                                                       \
      for (int mt = 0; mt < 4; ++mt)                                          \
        _Pragma("unroll")                                                     \
        for (int nt = 0; nt < 4; ++nt)                                        \
          acc[half * 4 + mt][nt] = MFMA16(af[mt], bfr[nt], acc[half * 4 + mt][nt]); \
    }                                                                         \
  }

  STAGE(0, 0)
#pragma unroll 1
  for (int t2 = 0; t2 < 16; ++t2) {
    barrier_vm_lgkm();            // staged buf0 landed; prev readers drained (WAR-safe)
    STAGE(1, t2 * 64 + 32)
    COMPUTE(0)
    barrier_vm_lgkm();
    if (t2 < 15) { STAGE(0, t2 * 64 + 64) }
    COMPUTE(1)
  }
#undef STAGE
#undef COMPUTE

  const int mat = n0 >> 10;       // bx 0-7 -> Q, 8-15 -> K, 16-23 -> V
  const int b = m0 >> 10;
  if (mat < 2) {
    ushort* outp = (mat == 0) ? qb : kb;
    const float* bias = (mat == 0) ? bq : bk;
#pragma unroll
    for (int mt = 0; mt < 8; ++mt) {
      int mbase = m0 + wm + 16 * mt + 4 * quad;
#pragma unroll
      for (int nt = 0; nt < 4; ++nt) {
        int n = n0 + wn + 16 * nt + l16;
        int o = n & 1023; int hh = o >> 6; int d = o & 63;
        float bsv = bias[o];
#pragma unroll
        for (int reg = 0; reg < 4; ++reg) {
          int l = (mbase + reg) & 1023;
          outp[(((size_t)(b * 16 + hh)) * 1024 + l) * 64 + d] = f2b(acc[mt][nt][reg] + bsv);
        }
      }
    }
  } else {
    // V: vt[d][l] layout — reg-quad is l-contiguous -> one 8B packed store each
#pragma unroll
    for (int mt = 0; mt < 8; ++mt) {
      int mbase = m0 + wm + 16 * mt + 4 * quad;
      int lb = mbase & 1023;      // multiple of 4 -> 8B aligned
#pragma unroll
      for (int nt = 0; nt < 4; ++nt) {
        int n = n0 + wn + 16 * nt + l16;
        int o = n & 1023; int hh = o >> 6; int d = o & 63;
        float bsv = bv[o];
        uint2 pk;
        pk.x = cvtpk(acc[mt][nt][0] + bsv, acc[mt][nt][1] + bsv);
        pk.y = cvtpk(acc[mt][nt][2] + bsv, acc[mt][nt][3] + bsv);
        *(uint2*)(vt + (((size_t)(b * 16 + hh)) * 64 + d) * 1024 + lb) = pk;
      }
    }
  }
}

// ---------------- Flash attention (round-7 code exactly; PINs reverted — r8 null)
#define KR  0
#define VR  8192
#define ER  16384
#define SER 28672
#define PR  35072

__global__ __launch_bounds__(256, 2) void attn_kernel(
    const ushort* __restrict__ qb, const ushort* __restrict__ kb,
    const ushort* __restrict__ vt, const ushort* __restrict__ eb,
    const float* __restrict__ mask, float* __restrict__ out) {
  __shared__ __align__(16) ushort sm[39168];
  const int tid = threadIdx.x;
  const int w = tid >> 6, lane = tid & 63, quad = lane >> 4, l16 = lane & 15;
  const int bh = blockIdx.y, b = bh >> 4, h = bh & 15;
  const int l0 = blockIdx.x * 64;

  const int srow = lane >> 3;                  // 0..7
  const int colb = ((lane & 7) ^ srow) * 8;    // swizzled 16B chunk on the global side
  const int row0 = w * 8 + srow;

  const ushort* kp = kb + ((size_t)bh * 1024 + row0) * 64 + colb;
  const ushort* vp = vt + ((size_t)bh * 64 + row0) * 1024 + colb;
  const float* maskp = mask + b * 1024 + l16;

  const int p0 = blockIdx.x % 3;               // E-ring segment of window start, it=0

  // ---- initial stage: Q -> PR, K(0) -> Kbuf0, V(0) -> Vbuf0, E window (128 rows)
  {
    const ushort* qp = qb + ((size_t)bh * 1024 + l0 + row0) * 64 + colb;
    gload16(qp,         sm + PR + w * 512);
    gload16(qp + 2048,  sm + PR + 2048 + w * 512);
    gload16(kp,         sm + KR + w * 512);
    gload16(kp + 2048,  sm + KR + 2048 + w * 512);
    gload16(vp,         sm + VR + w * 512);
    gload16(vp + 32768, sm + VR + 2048 + w * 512);
    const int t0i = l0 + 960;
#pragma unroll
    for (int c2 = 0; c2 < 4; ++c2) {
      int jb = w * 8 + 32 * c2;                // chunk base in window coords
      int seg = p0 + (jb >> 6); if (seg >= 3) seg -= 3;
      int t = t0i + jb + srow; if (t > 2046) t = 2046;
      gload16(eb + (size_t)t * 64 + colb, sm + ER + seg * 4096 + (jb & 63) * 64);
    }
  }

  // ---- hoisted per-thread constant addressing (swizzle term is lane-constant)
  const int lm7 = l16 & 7;
  const int swzq = (quad ^ lm7) * 8;           // cb=quad slice; cb=quad+4 is ^32
  int offR0[4], offR1[4];                      // rows 16nt+l16: K frags (S) + V frags (PV)
#pragma unroll
  for (int nt = 0; nt < 4; ++nt) {
    offR0[nt] = (16 * nt + l16) * 64 + swzq;
    offR1[nt] = offR0[nt] ^ 32;
  }
  const int offW0 = (w * 16 + l16) * 64 + swzq;   // row w*16+l16
  const int offW1 = offW0 ^ 32;
  const int offPW0 = PR + offW0, offPW1 = PR + offW1;  // same row in P region (Q, P-as-A)
  // K-as-A frags for phase B: slab (3-w) (so E-blocks match phase A's w..w+4)
  const int offWK0 = ((3 - w) * 16 + l16) * 64 + swzq;
  const int offWK1 = offWK0 ^ 32;
  int eoffA[5]; bool selA[5];                  // shared E-block frag offsets + seg select
#pragma unroll
  for (int i = 0; i < 5; ++i) {
    int ba = w + i;
    eoffA[i] = ((ba & 3) * 16 + l16) * 64 + swzq;  selA[i] = (ba & 4) != 0;
  }
  int offSW[5];                                // SE2c band-store addresses (slab 3-w)
#pragma unroll
  for (int i = 0; i < 5; ++i)
    offSW[i] = SER + (3 - w) * 1600 + (16 * i + l16) * 20 + 4 * quad;
  const int bbF = SER + (w * 16 + 4 * quad + 15 - l16) * 20 + l16;  // SE2c read base
  int addrP[4][4];                             // P-scatter addresses (full)
#pragma unroll
  for (int nt = 0; nt < 4; ++nt)
#pragma unroll
    for (int reg = 0; reg < 4; ++reg)
      addrP[nt][reg] = PR + (w * 16 + 4 * quad + reg) * 64
                     + (((2 * nt + (l16 >> 3)) ^ ((4 * quad + reg) & 7)) * 8) + lm7;
  int bidx[4]; bool bcnd[4];                   // bias1 bpermute constants
#pragma unroll
  for (int r = 0; r < 4; ++r) {
    bidx[r] = (quad * 16 + ((4 * quad + r + 15 - l16) & 15)) * 4;
    bcnd[r] = (4 * quad + r) > l16;
  }

  barrier_vm();  // init: all staging landed (no lgkm ops outstanding)

  // hoist Q A-fragments (PR region is reused for P only after the P scatter of it=0)
  const s16x8 aq0 = *(const s16x8*)(sm + offPW0);
  const s16x8 aq1 = *(const s16x8*)(sm + offPW1);

  float rsum[4];
  f32x4 o_acc[4];
#pragma unroll
  for (int r = 0; r < 4; ++r) rsum[r] = 0.f;
#pragma unroll
  for (int nt = 0; nt < 4; ++nt) o_acc[nt] = (f32x4){0.f, 0.f, 0.f, 0.f};
  const f32x4 ZACC = {0.f, 0.f, 0.f, 0.f};     // persistent zero C-operand

  const float LOG2E = 1.44269504088896f;
  const float SC = 0.125f * LOG2E;

  int s0 = p0;  // ring segment holding window start, decremented mod 3 per iter

#define ATTN_ITER(P)                                                               \
  {                                                                                \
    const int it = 2 * ith + (P);                                                  \
    const int r0 = it * 64;                                                        \
    if (it > 0) barrier_vm(); /* X: prefetch landed; prior ds_reads consumed */    \
    /* ---- prefetch it+1 into buf[1-P] + E seg (stays in flight across C) */      \
    {                                                                              \
      const int rn = (r0 + 64) & 1023;                                             \
      gload16(kp + rn * 64,        sm + KR + 4096 * (1 - (P)) + w * 512);          \
      gload16(kp + rn * 64 + 2048, sm + KR + 4096 * (1 - (P)) + 2048 + w * 512);   \
      gload16(vp + rn,             sm + VR + 4096 * (1 - (P)) + w * 512);          \
      gload16(vp + rn + 32768,     sm + VR + 4096 * (1 - (P)) + 2048 + w * 512);   \
      int pnew = s0 + 2; if (pnew >= 3) pnew -= 3;                                 \
      const int tb = l0 + 960 - r0 - 64;                                           \
      _Pragma("unroll")                                                            \
      for (int c2 = 0; c2 < 2; ++c2) {                                             \
        int o = w * 8 + 32 * c2;                                                   \
        int t = tb + o + srow; t = t < 0 ? 0 : (t > 2046 ? 2046 : t);              \
        gload16(eb + (size_t)t * 64 + colb, sm + ER + pnew * 4096 + o * 64);       \
      }                                                                            \
    }                                                                              \
    float mkv[4];                                                                  \
    _Pragma("unroll")                                                              \
    for (int nt = 0; nt < 4; ++nt) mkv[nt] = maskp[r0 + 16 * nt] * LOG2E;          \
    const int sA4 = s0 * 4096;                                                     \
    int sBi = s0 + 1; if (sBi >= 3) sBi -= 3;                                      \
    const int sB4 = sBi * 4096;                                                    \
    const ushort* KbP = sm + KR + 4096 * (P);                                      \
    /* ---- S = Q K^T (MFMA cluster 1) */                                          \
    __builtin_amdgcn_s_setprio(1);                                                 \
    f32x4 zv[4];                                                                   \
    _Pragma("unroll")                                                              \
    for (int nt = 0; nt < 4; ++nt) {                                               \
      s16x8 bk0 = *(const s16x8*)(KbP + offR0[nt]);                                \
      s16x8 bk1 = *(const s16x8*)(KbP + offR1[nt]);                                \
      f32x4 z = MFMA16(aq0, bk0, ZACC);                                            \
      zv[nt] = MFMA16(aq1, bk1, z);                                                \
    }                                                                              \
    /* ---- merged E phases: read E block ONCE, feed Q·E (bias1) and K·E (band) */ \
    const s16x8 ak0 = *(const s16x8*)(KbP + offWK0);                               \
    const s16x8 ak1 = *(const s16x8*)(KbP + offWK1);                               \
    f32x4 d1[5];                                                                   \
    _Pragma("unroll")                                                              \
    for (int i = 0; i < 5; ++i) {                                                  \
      int ea = (selA[i] ? sB4 : sA4) + eoffA[i];                                   \
      s16x8 be0 = *(const s16x8*)(sm + ER + ea);                                   \
      s16x8 be1 = *(const s16x8*)(sm + ER + (ea ^ 32));                            \
      f32x4 z = MFMA16(aq0, be0, ZACC);                                            \
      d1[i] = MFMA16(aq1, be1, z);                                                 \
      f32x4 y = MFMA16(ak0, be0, ZACC);                                            \
      y = MFMA16(ak1, be1, y);                                                     \
      uint2 pk; pk.x = pack2t(y[0], y[1]); pk.y = pack2t(y[2], y[3]);              \
      *(uint2*)(sm + offSW[i]) = pk;                                               \
    }                                                                              \
    __builtin_amdgcn_s_setprio(0);                                                 \
    /* ---- bias1 (Q-side) via intra-wave bpermute */                              \
    _Pragma("unroll")                                                              \
    for (int r = 0; r < 4; ++r) {                                                  \
      float bp[5];                                                                 \
      _Pragma("unroll")                                                            \
      for (int i = 0; i < 5; ++i)                                                  \
        bp[i] = __int_as_float(                                                    \
            __builtin_amdgcn_ds_bpermute(bidx[r], __float_as_int(d1[i][r])));      \
      _Pragma("unroll")                                                            \
      for (int nt = 0; nt < 4; ++nt)                                               \
        zv[nt][r] += bcnd[r] ? bp[4 - nt] : bp[3 - nt];                            \
    }                                                                              \
    barrier_lgkm();  /* C: SE2c visible; prefetches NOT drained */                 \
    /* ---- bias2 + scale + mask -> p = exp2(z2); static softmax */                \
    _Pragma("unroll")                                                              \
    for (int nt = 0; nt < 4; ++nt) {                                               \
      _Pragma("unroll")                                                            \
      for (int reg = 0; reg < 4; ++reg) {                                          \
        float z2 = (zv[nt][reg] + b2f(sm[bbF + nt * 1600 + reg * 20])) * SC        \
                 + mkv[nt];                                                        \
        float pe = exp2f(z2);                                                      \
        zv[nt][reg] = pe;                                                          \
        rsum[reg] += pe;                                                           \
      }                                                                            \
    }                                                                              \
    /* ---- P scatter (rows wave-private -> no barrier; cvt_pk pairs) */           \
    _Pragma("unroll")                                                              \
    for (int nt = 0; nt < 4; ++nt) {                                               \
      uint32_t u01 = cvtpk(zv[nt][0], zv[nt][1]);                                  \
      uint32_t u23 = cvtpk(zv[nt][2], zv[nt][3]);                                  \
      sm[addrP[nt][0]] = (ushort)u01;                                              \
      sm[addrP[nt][1]] = (ushort)(u01 >> 16);                                      \
      sm[addrP[nt][2]] = (ushort)u23;                                              \
      sm[addrP[nt][3]] = (ushort)(u23 >> 16);                                      \
    }                                                                              \
    /* ---- O += P @ V (MFMA cluster 3; same-wave DS order + lgkmcnt suffice) */   \
    __builtin_amdgcn_s_setprio(1);                                                 \
    {                                                                              \
      const ushort* VbP = sm + VR + 4096 * (P);                                    \
      const s16x8 ap0 = *(const s16x8*)(sm + offPW0);                              \
      _Pragma("unroll")                                                            \
      for (int nt = 0; nt < 4; ++nt) {                                             \
        s16x8 bv0 = *(const s16x8*)(VbP + offR0[nt]);                              \
        o_acc[nt] = MFMA16(ap0, bv0, o_acc[nt]);                                   \
      }                                                                            \
      const s16x8 ap1 = *(const s16x8*)(sm + offPW1);                              \
      _Pragma("unroll")                                                            \
      for (int nt = 0; nt < 4; ++nt) {                                             \
        s16x8 bv1 = *(const s16x8*)(VbP + offR1[nt]);                              \
        o_acc[nt] = MFMA16(ap1, bv1, o_acc[nt]);                                   \
      }                                                                            \
    }                                                                              \
    __builtin_amdgcn_s_setprio(0);                                                 \
    s0 = (s0 == 0) ? 2 : s0 - 1;  /* window slides down 64 rows */                 \
  }

#pragma unroll 1
  for (int ith = 0; ith < 8; ++ith) {
    ATTN_ITER(0)
    ATTN_ITER(1)
  }
#undef ATTN_ITER

  // ---- final denominator reduce (once, not per-iter) + store
#pragma unroll
  for (int off = 1; off < 16; off <<= 1)
#pragma unroll
    for (int reg = 0; reg < 4; ++reg)
      rsum[reg] += __shfl_xor(rsum[reg], off);

#pragma unroll
  for (int nt = 0; nt < 4; ++nt)
#pragma unroll
    for (int reg = 0; reg < 4; ++reg) {
      int l = l0 + w * 16 + 4 * quad + reg;
      int d = 16 * nt + l16;
      out[((size_t)(b * 1024 + l)) * 1024 + h * 64 + d] = o_acc[nt][reg] / rsum[reg];
    }
}

// ---------------- host launch
extern "C" void kernel_launch(void* const* d_in, const int* in_sizes, int n_in,
                              void* d_out, int out_size, void* d_ws, size_t ws_size,
                              hipStream_t stream) {
  const float* hidden = (const float*)d_in[0];
  const float* mask   = (const float*)d_in[1];
  const float* Wq     = (const float*)d_in[2];
  const float* bq     = (const float*)d_in[3];
  const float* Wk     = (const float*)d_in[4];
  const float* bk     = (const float*)d_in[5];
  const float* Wv     = (const float*)d_in[6];
  const float* bv     = (const float*)d_in[7];
  const float* dist   = (const float*)d_in[8];
  float* out = (float*)d_out;

  ushort* ws = (ushort*)d_ws;
  ushort* qb = ws;
  ushort* kb = ws + 8388608;
  ushort* vt = ws + 16777216;
  ushort* hb = ws + 25165824;
  ushort* wb = ws + 33554432;
  ushort* eb = ws + 36700160;

  cast_all<<<11392, 256, 0, stream>>>(hidden, Wq, Wk, Wv, dist, hb, wb, eb);
  qkv_gemm<<<768, 256, 0, stream>>>(hb, wb, bq, bk, bv, qb, kb, vt);
  attn_kernel<<<dim3(16, 128), 256, 0, stream>>>(qb, kb, vt, eb, mask, out);
}

// Round 11
// 339.519 us; speedup vs baseline: 1.0782x; 1.0018x over previous
//
#include <hip/hip_runtime.h>
#include <stdint.h>

typedef short s16x8 __attribute__((ext_vector_type(8)));
typedef float f32x4 __attribute__((ext_vector_type(4)));

#define MFMA16(a, b, c) __builtin_amdgcn_mfma_f32_16x16x32_bf16((a), (b), (c), 0, 0, 0)

__device__ __forceinline__ ushort f2b(float f) {
  union { float f; uint32_t u; } x; x.f = f;
  uint32_t r = x.u + 0x7fffu + ((x.u >> 16) & 1u);
  return (ushort)(r >> 16);
}
__device__ __forceinline__ float b2f(ushort s) {
  union { uint32_t u; float f; } x; x.u = ((uint32_t)s) << 16;
  return x.f;
}
__device__ __forceinline__ uint32_t pack2t(float a, float b) {
  return __builtin_amdgcn_perm(__float_as_uint(b), __float_as_uint(a), 0x07060302u);
}
// RNE-packed bf16 pair: lo = bf16(a), hi = bf16(b). No builtin on gfx950 (m240).
__device__ __forceinline__ uint32_t cvtpk(float a, float b) {
  uint32_t r;
  asm("v_cvt_pk_bf16_f32 %0, %1, %2" : "=v"(r) : "v"(a), "v"(b));
  return r;
}

// ---- barriers.
__device__ __forceinline__ void barrier_vm() {
  asm volatile("s_waitcnt vmcnt(0)" ::: "memory");
  __builtin_amdgcn_s_barrier();
}
__device__ __forceinline__ void barrier_vm_lgkm() {
  asm volatile("s_waitcnt vmcnt(0) lgkmcnt(0)" ::: "memory");
  __builtin_amdgcn_s_barrier();
}
__device__ __forceinline__ void barrier_lgkm() {
  asm volatile("s_waitcnt lgkmcnt(0)" ::: "memory");
  __builtin_amdgcn_s_barrier();
}

// ---- single fused cast kernel: hidden (8192 blks) + Wq/Wk/Wv (3x1024) + dist (128)
__global__ __launch_bounds__(256) void cast_all(
    const float* __restrict__ hidden, const float* __restrict__ wq,
    const float* __restrict__ wk, const float* __restrict__ wv,
    const float* __restrict__ dist,
    ushort* __restrict__ hb, ushort* __restrict__ wb, ushort* __restrict__ eb) {
  int blk = blockIdx.x;
  const float* src; ushort* dst; int n;
  if (blk < 8192)      { src = hidden; dst = hb; n = 8388608; }
  else if (blk < 9216) { src = wq; dst = wb;               n = 1048576; blk -= 8192; }
  else if (blk < 10240){ src = wk; dst = wb + 1048576;     n = 1048576; blk -= 9216; }
  else if (blk < 11264){ src = wv; dst = wb + 2097152;     n = 1048576; blk -= 10240; }
  else                 { src = dist; dst = eb;             n = 131008;  blk -= 11264; }
  int i = (blk * 256 + threadIdx.x) * 4;
  if (i + 4 <= n) {
    float4 v = *(const float4*)(src + i);
    ushort4 o; o.x = f2b(v.x); o.y = f2b(v.y); o.z = f2b(v.z); o.w = f2b(v.w);
    *(ushort4*)(dst + i) = o;
  }
}

__device__ __forceinline__ void gload16(const void* g, void* l) {
  __builtin_amdgcn_global_load_lds((const __attribute__((address_space(1))) void*)g,
                                   (__attribute__((address_space(3))) void*)l, 16, 0, 0);
}

// ---------------- QKV GEMM v7: v6 + T2 bank-conflict swizzle.
// r9 audit: the [row][32us] tile (64B row stride) makes each fragment read an
// 8-WAY bank conflict (16 lanes at dword-bank l16*16+quad*4 mod 32: 8 even
// lanes share one 4-bank group). Cost 2.94x (m136) on a ~23us DS floor = ~68us
// — the dominant gemm term (68 DS + 21 MFMA + ~15 stores ~= 112us measured;
// r9's -22us == the conflict-scaled DS delta exactly).
// Fix: store 16B-chunk c of row r at position c ^ ((r>>1)&3) (involution).
// gload_lds writes linearly -> swizzle the GLOBAL source per-lane (m173):
// lane fetches global chunk (lane&3)^((lane>>3)&3) (valid: the chunk's row key
// reduces to (lane>>3)&3). Read side adds lane-constant quad^((l16>>1)&3).
// Result: 2-way conflict (free, m136).
// (Resubmission: round-10 bench died to a container-acquire infra failure;
// swizzle algebra + bank mapping re-verified, no hang vectors in the diff.)
__global__ __launch_bounds__(256, 3) void qkv_gemm(
    const ushort* __restrict__ hb, const ushort* __restrict__ wb,
    const float* __restrict__ bq, const float* __restrict__ bk, const float* __restrict__ bv,
    ushort* __restrict__ qb, ushort* __restrict__ kb, ushort* __restrict__ vt) {
  __shared__ ushort As[2][8192];   // 256 rows x 32 us, chunk-swizzled
  __shared__ ushort Bs[2][4096];   // 128 rows x 32 us, chunk-swizzled
  const int tid = threadIdx.x;
  const int w = tid >> 6, lane = tid & 63, quad = lane >> 4, l16 = lane & 15;

  // bijective XCD swizzle (768 % 8 == 0): consecutive tiles share an A-panel
  const int wg = blockIdx.x;
  const int swz = (wg & 7) * 96 + (wg >> 3);
  const int by = swz / 24;
  const int bx = swz % 24;
  const int m0 = by * 256, n0 = bx * 128;

  // staging: 1KB wave-chunks, LINEAR LDS dest (gload_lds requirement);
  // global source column pre-swizzled so LDS pos p of row r holds chunk
  // p ^ ((r>>1)&3).
  const int arow = lane >> 2;
  const int acol = (((lane & 3) ^ ((lane >> 3) & 3)) * 8);   // T2 pre-swizzle
  const ushort* ga = hb + (size_t)(m0 + arow) * 1024 + acol;
  const ushort* gw = wb + (size_t)(n0 + arow) * 1024 + acol;

  f32x4 acc[8][4];
#pragma unroll
  for (int mt = 0; mt < 8; ++mt)
#pragma unroll
    for (int nt = 0; nt < 4; ++nt) acc[mt][nt] = (f32x4){0.f, 0.f, 0.f, 0.f};

  const int wm = (w >> 1) * 128, wn = (w & 1) * 64;
  const int rq = (quad ^ ((l16 >> 1) & 3)) * 8;   // swizzled read chunk (lane-const)

#define STAGE(C, K0)                                                      \
  gload16(ga + (K0) + (size_t)((w)      * 16) * 1024, As[C] + (w)      * 512); \
  gload16(ga + (K0) + (size_t)((w + 4)  * 16) * 1024, As[C] + (w + 4)  * 512); \
  gload16(ga + (K0) + (size_t)((w + 8)  * 16) * 1024, As[C] + (w + 8)  * 512); \
  gload16(ga + (K0) + (size_t)((w + 12) * 16) * 1024, As[C] + (w + 12) * 512); \
  gload16(gw + (K0) + (size_t)((w)      * 16) * 1024, Bs[C] + (w)      * 512); \
  gload16(gw + (K0) + (size_t)((w + 4)  * 16) * 1024, Bs[C] + (w + 4)  * 512);

#define COMPUTE(C)                                                            \
  {                                                                           \
    s16x8 bfr[4];                                                             \
    _Pragma("unroll")                                                         \
    for (int nt = 0; nt < 4; ++nt)                                            \
      bfr[nt] = *(const s16x8*)(Bs[C] + (wn + 16 * nt + l16) * 32 + rq);      \
    _Pragma("unroll")                                                         \
    for (int half = 0; half < 2; ++half) {                                    \
      s16x8 af[4];                                                            \
      _Pragma("unroll")                                                       \
      for (int mt = 0; mt < 4; ++mt)                                          \
        af[mt] = *(const s16x8*)(As[C] +                                      \
                    (wm + 64 * half + 16 * mt + l16) * 32 + rq);              \
      _Pragma("unroll")                                                       \
      for (int mt = 0; mt < 4; ++mt)                                          \
        _Pragma("unroll")                                                     \
        for (int nt = 0; nt < 4; ++nt)                                        \
          acc[half * 4 + mt][nt] = MFMA16(af[mt], bfr[nt], acc[half * 4 + mt][nt]); \
    }                                                                         \
  }

  STAGE(0, 0)
#pragma unroll 1
  for (int t2 = 0; t2 < 16; ++t2) {
    barrier_vm_lgkm();            // staged buf0 landed; prev readers drained (WAR-safe)
    STAGE(1, t2 * 64 + 32)
    COMPUTE(0)
    barrier_vm_lgkm();
    if (t2 < 15) { STAGE(0, t2 * 64 + 64) }
    COMPUTE(1)
  }
#undef STAGE
#undef COMPUTE

  const int mat = n0 >> 10;       // bx 0-7 -> Q, 8-15 -> K, 16-23 -> V
  const int b = m0 >> 10;
  if (mat < 2) {
    ushort* outp = (mat == 0) ? qb : kb;
    const float* bias = (mat == 0) ? bq : bk;
#pragma unroll
    for (int mt = 0; mt < 8; ++mt) {
      int mbase = m0 + wm + 16 * mt + 4 * quad;
#pragma unroll
      for (int nt = 0; nt < 4; ++nt) {
        int n = n0 + wn + 16 * nt + l16;
        int o = n & 1023; int hh = o >> 6; int d = o & 63;
        float bsv = bias[o];
#pragma unroll
        for (int reg = 0; reg < 4; ++reg) {
          int l = (mbase + reg) & 1023;
          outp[(((size_t)(b * 16 + hh)) * 1024 + l) * 64 + d] = f2b(acc[mt][nt][reg] + bsv);
        }
      }
    }
  } else {
    // V: vt[d][l] layout — reg-quad is l-contiguous -> one 8B packed store each
#pragma unroll
    for (int mt = 0; mt < 8; ++mt) {
      int mbase = m0 + wm + 16 * mt + 4 * quad;
      int lb = mbase & 1023;      // multiple of 4 -> 8B aligned
#pragma unroll
      for (int nt = 0; nt < 4; ++nt) {
        int n = n0 + wn + 16 * nt + l16;
        int o = n & 1023; int hh = o >> 6; int d = o & 63;
        float bsv = bv[o];
        uint2 pk;
        pk.x = cvtpk(acc[mt][nt][0] + bsv, acc[mt][nt][1] + bsv);
        pk.y = cvtpk(acc[mt][nt][2] + bsv, acc[mt][nt][3] + bsv);
        *(uint2*)(vt + (((size_t)(b * 16 + hh)) * 64 + d) * 1024 + lb) = pk;
      }
    }
  }
}

// ---------------- Flash attention (round-7 code exactly, unchanged)
#define KR  0
#define VR  8192
#define ER  16384
#define SER 28672
#define PR  35072

__global__ __launch_bounds__(256, 2) void attn_kernel(
    const ushort* __restrict__ qb, const ushort* __restrict__ kb,
    const ushort* __restrict__ vt, const ushort* __restrict__ eb,
    const float* __restrict__ mask, float* __restrict__ out) {
  __shared__ __align__(16) ushort sm[39168];
  const int tid = threadIdx.x;
  const int w = tid >> 6, lane = tid & 63, quad = lane >> 4, l16 = lane & 15;
  const int bh = blockIdx.y, b = bh >> 4, h = bh & 15;
  const int l0 = blockIdx.x * 64;

  const int srow = lane >> 3;                  // 0..7
  const int colb = ((lane & 7) ^ srow) * 8;    // swizzled 16B chunk on the global side
  const int row0 = w * 8 + srow;

  const ushort* kp = kb + ((size_t)bh * 1024 + row0) * 64 + colb;
  const ushort* vp = vt + ((size_t)bh * 64 + row0) * 1024 + colb;
  const float* maskp = mask + b * 1024 + l16;

  const int p0 = blockIdx.x % 3;               // E-ring segment of window start, it=0

  // ---- initial stage: Q -> PR, K(0) -> Kbuf0, V(0) -> Vbuf0, E window (128 rows)
  {
    const ushort* qp = qb + ((size_t)bh * 1024 + l0 + row0) * 64 + colb;
    gload16(qp,         sm + PR + w * 512);
    gload16(qp + 2048,  sm + PR + 2048 + w * 512);
    gload16(kp,         sm + KR + w * 512);
    gload16(kp + 2048,  sm + KR + 2048 + w * 512);
    gload16(vp,         sm + VR + w * 512);
    gload16(vp + 32768, sm + VR + 2048 + w * 512);
    const int t0i = l0 + 960;
#pragma unroll
    for (int c2 = 0; c2 < 4; ++c2) {
      int jb = w * 8 + 32 * c2;                // chunk base in window coords
      int seg = p0 + (jb >> 6); if (seg >= 3) seg -= 3;
      int t = t0i + jb + srow; if (t > 2046) t = 2046;
      gload16(eb + (size_t)t * 64 + colb, sm + ER + seg * 4096 + (jb & 63) * 64);
    }
  }

  // ---- hoisted per-thread constant addressing (swizzle term is lane-constant)
  const int lm7 = l16 & 7;
  const int swzq = (quad ^ lm7) * 8;           // cb=quad slice; cb=quad+4 is ^32
  int offR0[4], offR1[4];                      // rows 16nt+l16: K frags (S) + V frags (PV)
#pragma unroll
  for (int nt = 0; nt < 4; ++nt) {
    offR0[nt] = (16 * nt + l16) * 64 + swzq;
    offR1[nt] = offR0[nt] ^ 32;
  }
  const int offW0 = (w * 16 + l16) * 64 + swzq;   // row w*16+l16
  const int offW1 = offW0 ^ 32;
  const int offPW0 = PR + offW0, offPW1 = PR + offW1;  // same row in P region (Q, P-as-A)
  // K-as-A frags for phase B: slab (3-w) (so E-blocks match phase A's w..w+4)
  const int offWK0 = ((3 - w) * 16 + l16) * 64 + swzq;
  const int offWK1 = offWK0 ^ 32;
  int eoffA[5]; bool selA[5];                  // shared E-block frag offsets + seg select
#pragma unroll
  for (int i = 0; i < 5; ++i) {
    int ba = w + i;
    eoffA[i] = ((ba & 3) * 16 + l16) * 64 + swzq;  selA[i] = (ba & 4) != 0;
  }
  int offSW[5];                                // SE2c band-store addresses (slab 3-w)
#pragma unroll
  for (int i = 0; i < 5; ++i)
    offSW[i] = SER + (3 - w) * 1600 + (16 * i + l16) * 20 + 4 * quad;
  const int bbF = SER + (w * 16 + 4 * quad + 15 - l16) * 20 + l16;  // SE2c read base
  int addrP[4][4];                             // P-scatter addresses (full)
#pragma unroll
  for (int nt = 0; nt < 4; ++nt)
#pragma unroll
    for (int reg = 0; reg < 4; ++reg)
      addrP[nt][reg] = PR + (w * 16 + 4 * quad + reg) * 64
                     + (((2 * nt + (l16 >> 3)) ^ ((4 * quad + reg) & 7)) * 8) + lm7;
  int bidx[4]; bool bcnd[4];                   // bias1 bpermute constants
#pragma unroll
  for (int r = 0; r < 4; ++r) {
    bidx[r] = (quad * 16 + ((4 * quad + r + 15 - l16) & 15)) * 4;
    bcnd[r] = (4 * quad + r) > l16;
  }

  barrier_vm();  // init: all staging landed (no lgkm ops outstanding)

  // hoist Q A-fragments (PR region is reused for P only after the P scatter of it=0)
  const s16x8 aq0 = *(const s16x8*)(sm + offPW0);
  const s16x8 aq1 = *(const s16x8*)(sm + offPW1);

  float rsum[4];
  f32x4 o_acc[4];
#pragma unroll
  for (int r = 0; r < 4; ++r) rsum[r] = 0.f;
#pragma unroll
  for (int nt = 0; nt < 4; ++nt) o_acc[nt] = (f32x4){0.f, 0.f, 0.f, 0.f};
  const f32x4 ZACC = {0.f, 0.f, 0.f, 0.f};     // persistent zero C-operand

  const float LOG2E = 1.44269504088896f;
  const float SC = 0.125f * LOG2E;

  int s0 = p0;  // ring segment holding window start, decremented mod 3 per iter

#define ATTN_ITER(P)                                                               \
  {                                                                                \
    const int it = 2 * ith + (P);                                                  \
    const int r0 = it * 64;                                                        \
    if (it > 0) barrier_vm(); /* X: prefetch landed; prior ds_reads consumed */    \
    /* ---- prefetch it+1 into buf[1-P] + E seg (stays in flight across C) */      \
    {                                                                              \
      const int rn = (r0 + 64) & 1023;                                             \
      gload16(kp + rn * 64,        sm + KR + 4096 * (1 - (P)) + w * 512);          \
      gload16(kp + rn * 64 + 2048, sm + KR + 4096 * (1 - (P)) + 2048 + w * 512);   \
      gload16(vp + rn,             sm + VR + 4096 * (1 - (P)) + w * 512);          \
      gload16(vp + rn + 32768,     sm + VR + 4096 * (1 - (P)) + 2048 + w * 512);   \
      int pnew = s0 + 2; if (pnew >= 3) pnew -= 3;                                 \
      const int tb = l0 + 960 - r0 - 64;                                           \
      _Pragma("unroll")                                                            \
      for (int c2 = 0; c2 < 2; ++c2) {                                             \
        int o = w * 8 + 32 * c2;                                                   \
        int t = tb + o + srow; t = t < 0 ? 0 : (t > 2046 ? 2046 : t);              \
        gload16(eb + (size_t)t * 64 + colb, sm + ER + pnew * 4096 + o * 64);       \
      }                                                                            \
    }                                                                              \
    float mkv[4];                                                                  \
    _Pragma("unroll")                                                              \
    for (int nt = 0; nt < 4; ++nt) mkv[nt] = maskp[r0 + 16 * nt] * LOG2E;          \
    const int sA4 = s0 * 4096;                                                     \
    int sBi = s0 + 1; if (sBi >= 3) sBi -= 3;                                      \
    const int sB4 = sBi * 4096;                                                    \
    const ushort* KbP = sm + KR + 4096 * (P);                                      \
    /* ---- S = Q K^T (MFMA cluster 1) */                                          \
    __builtin_amdgcn_s_setprio(1);                                                 \
    f32x4 zv[4];                                                                   \
    _Pragma("unroll")                                                              \
    for (int nt = 0; nt < 4; ++nt) {                                               \
      s16x8 bk0 = *(const s16x8*)(KbP + offR0[nt]);                                \
      s16x8 bk1 = *(const s16x8*)(KbP + offR1[nt]);                                \
      f32x4 z = MFMA16(aq0, bk0, ZACC);                                            \
      zv[nt] = MFMA16(aq1, bk1, z);                                                \
    }                                                                              \
    /* ---- merged E phases: read E block ONCE, feed Q·E (bias1) and K·E (band) */ \
    const s16x8 ak0 = *(const s16x8*)(KbP + offWK0);                               \
    const s16x8 ak1 = *(const s16x8*)(KbP + offWK1);                               \
    f32x4 d1[5];                                                                   \
    _Pragma("unroll")                                                              \
    for (int i = 0; i < 5; ++i) {                                                  \
      int ea = (selA[i] ? sB4 : sA4) + eoffA[i];                                   \
      s16x8 be0 = *(const s16x8*)(sm + ER + ea);                                   \
      s16x8 be1 = *(const s16x8*)(sm + ER + (ea ^ 32));                            \
      f32x4 z = MFMA16(aq0, be0, ZACC);                                            \
      d1[i] = MFMA16(aq1, be1, z);                                                 \
      f32x4 y = MFMA16(ak0, be0, ZACC);                                            \
      y = MFMA16(ak1, be1, y);                                                     \
      uint2 pk; pk.x = pack2t(y[0], y[1]); pk.y = pack2t(y[2], y[3]);              \
      *(uint2*)(sm + offSW[i]) = pk;                                               \
    }                                                                              \
    __builtin_amdgcn_s_setprio(0);                                                 \
    /* ---- bias1 (Q-side) via intra-wave bpermute */                              \
    _Pragma("unroll")                                                              \
    for (int r = 0; r < 4; ++r) {                                                  \
      float bp[5];                                                                 \
      _Pragma("unroll")                                                            \
      for (int i = 0; i < 5; ++i)                                                  \
        bp[i] = __int_as_float(                                                    \
            __builtin_amdgcn_ds_bpermute(bidx[r], __float_as_int(d1[i][r])));      \
      _Pragma("unroll")                                                            \
      for (int nt = 0; nt < 4; ++nt)                                               \
        zv[nt][r] += bcnd[r] ? bp[4 - nt] : bp[3 - nt];                            \
    }                                                                              \
    barrier_lgkm();  /* C: SE2c visible; prefetches NOT drained */                 \
    /* ---- bias2 + scale + mask -> p = exp2(z2); static softmax */                \
    _Pragma("unroll")                                                              \
    for (int nt = 0; nt < 4; ++nt) {                                               \
      _Pragma("unroll")                                                            \
      for (int reg = 0; reg < 4; ++reg) {                                          \
        float z2 = (zv[nt][reg] + b2f(sm[bbF + nt * 1600 + reg * 20])) * SC        \
                 + mkv[nt];                                                        \
        float pe = exp2f(z2);                                                      \
        zv[nt][reg] = pe;                                                          \
        rsum[reg] += pe;                                                           \
      }                                                                            \
    }                                                                              \
    /* ---- P scatter (rows wave-private -> no barrier; cvt_pk pairs) */           \
    _Pragma("unroll")                                                              \
    for (int nt = 0; nt < 4; ++nt) {                                               \
      uint32_t u01 = cvtpk(zv[nt][0], zv[nt][1]);                                  \
      uint32_t u23 = cvtpk(zv[nt][2], zv[nt][3]);                                  \
      sm[addrP[nt][0]] = (ushort)u01;                                              \
      sm[addrP[nt][1]] = (ushort)(u01 >> 16);                                      \
      sm[addrP[nt][2]] = (ushort)u23;                                              \
      sm[addrP[nt][3]] = (ushort)(u23 >> 16);                                      \
    }                                                                              \
    /* ---- O += P @ V (MFMA cluster 3; same-wave DS order + lgkmcnt suffice) */   \
    __builtin_amdgcn_s_setprio(1);                                                 \
    {                                                                              \
      const ushort* VbP = sm + VR + 4096 * (P);                                    \
      const s16x8 ap0 = *(const s16x8*)(sm + offPW0);                              \
      _Pragma("unroll")                                                            \
      for (int nt = 0; nt < 4; ++nt) {                                             \
        s16x8 bv0 = *(const s16x8*)(VbP + offR0[nt]);                              \
        o_acc[nt] = MFMA16(ap0, bv0, o_acc[nt]);                                   \
      }                                                                            \
      const s16x8 ap1 = *(const s16x8*)(sm + offPW1);                              \
      _Pragma("unroll")                                                            \
      for (int nt = 0; nt < 4; ++nt) {                                             \
        s16x8 bv1 = *(const s16x8*)(VbP + offR1[nt]);                              \
        o_acc[nt] = MFMA16(ap1, bv1, o_acc[nt]);                                   \
      }                                                                            \
    }                                                                              \
    __builtin_amdgcn_s_setprio(0);                                                 \
    s0 = (s0 == 0) ? 2 : s0 - 1;  /* window slides down 64 rows */                 \
  }

#pragma unroll 1
  for (int ith = 0; ith < 8; ++ith) {
    ATTN_ITER(0)
    ATTN_ITER(1)
  }
#undef ATTN_ITER

  // ---- final denominator reduce (once, not per-iter) + store
#pragma unroll
  for (int off = 1; off < 16; off <<= 1)
#pragma unroll
    for (int reg = 0; reg < 4; ++reg)
      rsum[reg] += __shfl_xor(rsum[reg], off);

#pragma unroll
  for (int nt = 0; nt < 4; ++nt)
#pragma unroll
    for (int reg = 0; reg < 4; ++reg) {
      int l = l0 + w * 16 + 4 * quad + reg;
      int d = 16 * nt + l16;
      out[((size_t)(b * 1024 + l)) * 1024 + h * 64 + d] = o_acc[nt][reg] / rsum[reg];
    }
}

// ---------------- host launch
extern "C" void kernel_launch(void* const* d_in, const int* in_sizes, int n_in,
                              void* d_out, int out_size, void* d_ws, size_t ws_size,
                              hipStream_t stream) {
  const float* hidden = (const float*)d_in[0];
  const float* mask   = (const float*)d_in[1];
  const float* Wq     = (const float*)d_in[2];
  const float* bq     = (const float*)d_in[3];
  const float* Wk     = (const float*)d_in[4];
  const float* bk     = (const float*)d_in[5];
  const float* Wv     = (const float*)d_in[6];
  const float* bv     = (const float*)d_in[7];
  const float* dist   = (const float*)d_in[8];
  float* out = (float*)d_out;

  ushort* ws = (ushort*)d_ws;
  ushort* qb = ws;
  ushort* kb = ws + 8388608;
  ushort* vt = ws + 16777216;
  ushort* hb = ws + 25165824;
  ushort* wb = ws + 33554432;
  ushort* eb = ws + 36700160;

  cast_all<<<11392, 256, 0, stream>>>(hidden, Wq, Wk, Wv, dist, hb, wb, eb);
  qkv_gemm<<<768, 256, 0, stream>>>(hb, wb, bq, bk, bv, qb, kb, vt);
  attn_kernel<<<dim3(16, 128), 256, 0, stream>>>(qb, kb, vt, eb, mask, out);
}